// Round 7
// baseline (281.150 us; speedup 1.0000x reference)
//
#include <hip/hip_runtime.h>
#include <hip/hip_bf16.h>

typedef __attribute__((ext_vector_type(8))) short bf16x8;
typedef __attribute__((ext_vector_type(4))) float f32x4;

#define B_ 2
#define S_ 2048
#define D_ 1024
#define H_ 16
#define HD_ 64
#define M_ 4096
#define NEGV (-10000.0f)

static __device__ __forceinline__ unsigned short f2bf(float x) {
  __hip_bfloat16 h = __float2bfloat16(x);
  return *reinterpret_cast<unsigned short*>(&h);
}

static __device__ __forceinline__ bf16x8 cvt8(const float* p) {
  float4 a = *reinterpret_cast<const float4*>(p);
  float4 b = *reinterpret_cast<const float4*>(p + 4);
  bf16x8 r;
  r[0] = (short)f2bf(a.x); r[1] = (short)f2bf(a.y);
  r[2] = (short)f2bf(a.z); r[3] = (short)f2bf(a.w);
  r[4] = (short)f2bf(b.x); r[5] = (short)f2bf(b.y);
  r[6] = (short)f2bf(b.z); r[7] = (short)f2bf(b.w);
  return r;
}

// C = A(4096,1024) @ B(1024,1024)^T, bf16 MFMA, f32 accumulate.
// AF32/BF32: operand is f32 (cvt on stage); else bf16.
// MODE 0: **f32** row-major (final output; d_out is FLOAT32 -- ref returns f32)
// MODE 1: bf16 head-split dst[((b*H+h)*S + s)*HD + d]   (Q, K)
// MODE 2: bf16 transposed  dst[((b*H+h)*HD + d)*S + s]   (V)
// HSPLIT: A is bf16 stored head-split (ctx from attention).
template<int MODE, bool AF32, bool BF32, bool HSPLIT>
__global__ __launch_bounds__(256) void gemm_bt(const void* __restrict__ Av,
                                               const void* __restrict__ Bv,
                                               void* __restrict__ Cout) {
  constexpr int BK = 32, LDT = 40;  // +8 pad: row stride 80B -> 2-way bank alias (free)
  constexpr int K = 1024, N = 1024;
  __shared__ unsigned short Asm[128 * LDT];
  __shared__ unsigned short Bsm[128 * LDT];
  const int tid = threadIdx.x;
  const int lane = tid & 63, wid = tid >> 6;
  const int wm = wid >> 1, wn = wid & 1;
  const int l15 = lane & 15, l4 = lane >> 4;
  const int m0 = blockIdx.y * 128, n0 = blockIdx.x * 128;
  f32x4 acc[4][4] = {};

  for (int k0 = 0; k0 < K; k0 += BK) {
    __syncthreads();
#pragma unroll
    for (int i = 0; i < 2; ++i) {
      int idx = tid + 256 * i;          // 512 chunks of 8 elems = 128x32 tile
      int row = idx >> 2, k8 = (idx & 3) * 8;
      bf16x8 va, vb;
      if constexpr (AF32) {
        va = cvt8((const float*)Av + (size_t)(m0 + row) * K + k0 + k8);
      } else if constexpr (HSPLIT) {
        const int m = m0 + row, kk = k0 + k8;
        const int bb = m >> 11, s = m & 2047;
        va = *reinterpret_cast<const bf16x8*>(
            (const unsigned short*)Av +
            (((size_t)(bb * H_ + (kk >> 6)) * S_ + s) * HD_ + (kk & 63)));
      } else {
        va = *reinterpret_cast<const bf16x8*>((const unsigned short*)Av + (size_t)(m0 + row) * K + k0 + k8);
      }
      if constexpr (BF32) {
        vb = cvt8((const float*)Bv + (size_t)(n0 + row) * K + k0 + k8);
      } else {
        vb = *reinterpret_cast<const bf16x8*>((const unsigned short*)Bv + (size_t)(n0 + row) * K + k0 + k8);
      }
      *reinterpret_cast<bf16x8*>(&Asm[row * LDT + k8]) = va;
      *reinterpret_cast<bf16x8*>(&Bsm[row * LDT + k8]) = vb;
    }
    __syncthreads();
    bf16x8 af[4], bfr[4];
#pragma unroll
    for (int f = 0; f < 4; ++f) {
      af[f]  = *reinterpret_cast<const bf16x8*>(&Asm[(wm * 64 + f * 16 + l15) * LDT + l4 * 8]);
      bfr[f] = *reinterpret_cast<const bf16x8*>(&Bsm[(wn * 64 + f * 16 + l15) * LDT + l4 * 8]);
    }
#pragma unroll
    for (int fm = 0; fm < 4; ++fm)
#pragma unroll
      for (int fn = 0; fn < 4; ++fn)
        acc[fm][fn] = __builtin_amdgcn_mfma_f32_16x16x32_bf16(af[fm], bfr[fn], acc[fm][fn], 0, 0, 0);
  }

#pragma unroll
  for (int fm = 0; fm < 4; ++fm) {
#pragma unroll
    for (int fn = 0; fn < 4; ++fn) {
      const int mg0 = m0 + wm * 64 + fm * 16 + l4 * 4;   // rows mg0..mg0+3
      const int ng  = n0 + wn * 64 + fn * 16 + l15;
      if constexpr (MODE == 0) {
        float* C = (float*)Cout;                    // FLOAT32 final output
#pragma unroll
        for (int r = 0; r < 4; ++r)
          C[(size_t)(mg0 + r) * N + ng] = acc[fm][fn][r];
      } else if constexpr (MODE == 1) {
        unsigned short* C = (unsigned short*)Cout;
        const int bidx = mg0 >> 11, s = mg0 & 2047;
        const int h = ng >> 6, d = ng & 63;
#pragma unroll
        for (int r = 0; r < 4; ++r)
          C[((size_t)((bidx * H_ + h) * S_ + s + r)) * HD_ + d] = f2bf(acc[fm][fn][r]);
      } else {
        unsigned short* C = (unsigned short*)Cout;
        const int bidx = mg0 >> 11, s = mg0 & 2047;
        const int h = ng >> 6, d = ng & 63;
        ushort4 pk;
        pk.x = f2bf(acc[fm][fn][0]); pk.y = f2bf(acc[fm][fn][1]);
        pk.z = f2bf(acc[fm][fn][2]); pk.w = f2bf(acc[fm][fn][3]);
        *reinterpret_cast<ushort4*>(&C[((size_t)((bidx * H_ + h) * HD_ + d)) * S_ + s]) = pk;
      }
    }
  }
}

// Flash-style MFMA attention over ALL key tiles (exact reference mask
// semantics). Block: 4 waves, 64 q-rows (wave w owns 16). Grid: (S/64, B*H).
// ctx (head-split, same layout as Qh) MAY ALIAS Qh: each wave reads only its
// own 16 Q-rows (into regs at start) and writes exactly those rows at the end.
__global__ __launch_bounds__(256) void attn_fwd(const unsigned short* Qh,
                                                const unsigned short* __restrict__ Kh,
                                                const unsigned short* __restrict__ Vt,
                                                const int* __restrict__ attn_mask,
                                                const int* __restrict__ mask_future,
                                                unsigned short* ctx) {
  constexpr int LDK = 72;  // 64+8 pad: row stride 144B -> 2-way bank alias (free)
  __shared__ unsigned short Ksm[64 * LDK];
  __shared__ unsigned short Vsm[64 * LDK];   // d-major: Vsm[d][s_off]
  __shared__ unsigned short Psm[4][16 * LDK];
  __shared__ int msk[64];
  const int tid = threadIdx.x, lane = tid & 63, wid = tid >> 6;
  const int l15 = lane & 15, l4 = lane >> 4;
  const int bh = blockIdx.y, b = bh >> 4;
  const int q0 = blockIdx.x * 64;
  const bool causal = (mask_future[0] != 0);

  const unsigned short* Qb = Qh + (size_t)bh * S_ * HD_;
  const unsigned short* Kb = Kh + (size_t)bh * S_ * HD_;
  const unsigned short* Vb = Vt + (size_t)bh * HD_ * S_;

  const int qrow = q0 + wid * 16 + l15;
  const bf16x8 qf0 = *reinterpret_cast<const bf16x8*>(&Qb[(size_t)qrow * HD_ + l4 * 8]);
  const bf16x8 qf1 = *reinterpret_cast<const bf16x8*>(&Qb[(size_t)qrow * HD_ + 32 + l4 * 8]);

  float m_run[4], l_run[4];
  f32x4 o[4] = {};
#pragma unroll
  for (int r = 0; r < 4; ++r) { m_run[r] = -1e30f; l_run[r] = 0.f; }

  for (int kb = 0; kb < S_; kb += 64) {
    __syncthreads();
#pragma unroll
    for (int i = 0; i < 2; ++i) {
      int idx = tid + 256 * i;          // 512 chunks of 8 = 64x64 tile
      int row = idx >> 3, c8 = (idx & 7) * 8;
      *reinterpret_cast<bf16x8*>(&Ksm[row * LDK + c8]) =
          *reinterpret_cast<const bf16x8*>(&Kb[(size_t)(kb + row) * HD_ + c8]);
      *reinterpret_cast<bf16x8*>(&Vsm[row * LDK + c8]) =
          *reinterpret_cast<const bf16x8*>(&Vb[(size_t)row * S_ + kb + c8]);
    }
    if (tid < 64) msk[tid] = attn_mask[b * S_ + kb + tid];
    __syncthreads();

    // QK^T: D[q=(l>>4)*4+r][key=l&15] per 16-col fragment
    f32x4 sc[4];
#pragma unroll
    for (int nf = 0; nf < 4; ++nf) {
      bf16x8 kf0 = *reinterpret_cast<const bf16x8*>(&Ksm[(nf * 16 + l15) * LDK + l4 * 8]);
      bf16x8 kf1 = *reinterpret_cast<const bf16x8*>(&Ksm[(nf * 16 + l15) * LDK + 32 + l4 * 8]);
      f32x4 z = {};
      z = __builtin_amdgcn_mfma_f32_16x16x32_bf16(qf0, kf0, z, 0, 0, 0);
      z = __builtin_amdgcn_mfma_f32_16x16x32_bf16(qf1, kf1, z, 0, 0, 0);
      sc[nf] = z;
    }

    float p[4][4];
#pragma unroll
    for (int r = 0; r < 4; ++r) {
      const int rowg = q0 + wid * 16 + l4 * 4 + r;
      float mx = -1e30f;
#pragma unroll
      for (int nf = 0; nf < 4; ++nf) {
        const int colg = kb + nf * 16 + l15;
        float vv = sc[nf][r] * 0.125f;               // 1/sqrt(64)
        if (causal && colg > rowg) vv += NEGV;       // causal bias (additive)
        if (msk[nf * 16 + l15] == 0) vv = NEGV;      // pad mask (replace)
        p[nf][r] = vv;
        mx = fmaxf(mx, vv);
      }
      mx = fmaxf(mx, __shfl_xor(mx, 1));
      mx = fmaxf(mx, __shfl_xor(mx, 2));
      mx = fmaxf(mx, __shfl_xor(mx, 4));
      mx = fmaxf(mx, __shfl_xor(mx, 8));
      const float m_new = fmaxf(m_run[r], mx);
      const float scale = __expf(m_run[r] - m_new);
      float s_loc = 0.f;
#pragma unroll
      for (int nf = 0; nf < 4; ++nf) {
        float e = __expf(p[nf][r] - m_new);
        p[nf][r] = e;
        s_loc += e;
      }
      s_loc += __shfl_xor(s_loc, 1);
      s_loc += __shfl_xor(s_loc, 2);
      s_loc += __shfl_xor(s_loc, 4);
      s_loc += __shfl_xor(s_loc, 8);
      l_run[r] = l_run[r] * scale + s_loc;
      m_run[r] = m_new;
#pragma unroll
      for (int nf2 = 0; nf2 < 4; ++nf2) o[nf2][r] *= scale;
    }

    // P (C/D layout) -> LDS -> A-fragment layout
    unsigned short* Pw = &Psm[wid][0];
#pragma unroll
    for (int nf = 0; nf < 4; ++nf)
#pragma unroll
      for (int r = 0; r < 4; ++r)
        Pw[(l4 * 4 + r) * LDK + nf * 16 + l15] = f2bf(p[nf][r]);
    __syncthreads();

    const bf16x8 pf0 = *reinterpret_cast<const bf16x8*>(&Pw[l15 * LDK + l4 * 8]);
    const bf16x8 pf1 = *reinterpret_cast<const bf16x8*>(&Pw[l15 * LDK + 32 + l4 * 8]);
#pragma unroll
    for (int nf2 = 0; nf2 < 4; ++nf2) {
      bf16x8 vf0 = *reinterpret_cast<const bf16x8*>(&Vsm[(nf2 * 16 + l15) * LDK + l4 * 8]);
      bf16x8 vf1 = *reinterpret_cast<const bf16x8*>(&Vsm[(nf2 * 16 + l15) * LDK + 32 + l4 * 8]);
      o[nf2] = __builtin_amdgcn_mfma_f32_16x16x32_bf16(pf0, vf0, o[nf2], 0, 0, 0);
      o[nf2] = __builtin_amdgcn_mfma_f32_16x16x32_bf16(pf1, vf1, o[nf2], 0, 0, 0);
    }
  }

  // ctx write: head-split layout, rows q0..q0+63 of slice bh (in-place over Qh)
#pragma unroll
  for (int nf2 = 0; nf2 < 4; ++nf2)
#pragma unroll
    for (int r = 0; r < 4; ++r) {
      const int rowg = q0 + wid * 16 + l4 * 4 + r;
      float vv = o[nf2][r] / l_run[r];
      ctx[((size_t)bh * S_ + rowg) * HD_ + nf2 * 16 + l15] = f2bf(vv);
    }
}

extern "C" void kernel_launch(void* const* d_in, const int* in_sizes, int n_in,
                              void* d_out, int out_size, void* d_ws, size_t ws_size,
                              hipStream_t stream) {
  const float* q = (const float*)d_in[0];
  const float* k = (const float*)d_in[1];
  const float* v = (const float*)d_in[2];
  const int* attn_mask = (const int*)d_in[3];
  const float* Wq = (const float*)d_in[4];
  const float* Wk = (const float*)d_in[5];
  const float* Wv = (const float*)d_in[6];
  const float* Wo = (const float*)d_in[7];
  const int* mask_future = (const int*)d_in[8];

  // d_out is FLOAT32 (reference returns f32): 4.19M elems = 16.78 MB.
  // Buffer plan (needs 16.78 MB of ws):
  //   ws0: Qh bf16 (Q-proj) -> overwritten IN PLACE by ctx (head-split)
  //   ws1: Kh bf16 (K-proj)
  //   d_out first half: Vt bf16 (V-proj, transposed) -> dead after attn,
  //        then the O-proj GEMM overwrites ALL of d_out with f32 output.
  const size_t n16 = (size_t)M_ * D_;
  unsigned short* ws0 = (unsigned short*)d_ws;
  unsigned short* ws1 = ws0 + n16;
  unsigned short* Vt  = (unsigned short*)d_out;
  float* out = (float*)d_out;
  (void)in_sizes; (void)n_in; (void)out_size; (void)ws_size;

  dim3 gg(D_ / 128, M_ / 128);   // (8, 32)
  gemm_bt<1, true,  true,  false><<<gg, 256, 0, stream>>>(q, Wq, ws0);
  gemm_bt<1, true,  true,  false><<<gg, 256, 0, stream>>>(k, Wk, ws1);
  gemm_bt<2, true,  true,  false><<<gg, 256, 0, stream>>>(v, Wv, Vt);
  attn_fwd<<<dim3(S_ / 64, B_ * H_), 256, 0, stream>>>(ws0, ws1, Vt, attn_mask, mask_future, ws0);
  gemm_bt<0, false, true,  true ><<<gg, 256, 0, stream>>>(ws0, Wo, out);
}

// Round 8
// 259.433 us; speedup vs baseline: 1.0837x; 1.0837x over previous
//
#include <hip/hip_runtime.h>
#include <hip/hip_bf16.h>

typedef __attribute__((ext_vector_type(8))) short bf16x8;
typedef __attribute__((ext_vector_type(4))) float f32x4;

#define B_ 2
#define S_ 2048
#define D_ 1024
#define H_ 16
#define HD_ 64
#define M_ 4096
#define NEGV (-10000.0f)

static __device__ __forceinline__ unsigned short f2bf(float x) {
  __hip_bfloat16 h = __float2bfloat16(x);
  return *reinterpret_cast<unsigned short*>(&h);
}

static __device__ __forceinline__ bf16x8 cvt8(const float* p) {
  float4 a = *reinterpret_cast<const float4*>(p);
  float4 b = *reinterpret_cast<const float4*>(p + 4);
  bf16x8 r;
  r[0] = (short)f2bf(a.x); r[1] = (short)f2bf(a.y);
  r[2] = (short)f2bf(a.z); r[3] = (short)f2bf(a.w);
  r[4] = (short)f2bf(b.x); r[5] = (short)f2bf(b.y);
  r[6] = (short)f2bf(b.z); r[7] = (short)f2bf(b.w);
  return r;
}

// C = A(4096,1024) @ B(1024,1024)^T, bf16 MFMA, f32 accumulate. BK=64.
// AF32/BF32: operand is f32 (cvt on stage); else bf16.
// MODE 0: f32 row-major (final output; d_out is FLOAT32)
// MODE 1: bf16 head-split dst[((b*H+h)*S + s)*HD + d]   (Q, K)
// MODE 2: bf16 transposed  dst[((b*H+h)*HD + d)*S + s]   (V)
// HSPLIT: A is bf16 stored head-split (ctx from attention).
template<int MODE, bool AF32, bool BF32, bool HSPLIT>
__global__ __launch_bounds__(256) void gemm_bt(const void* __restrict__ Av,
                                               const void* __restrict__ Bv,
                                               void* __restrict__ Cout) {
  constexpr int BK = 64, LDT = 72;  // +8 pad: row stride 144B -> 2-way alias
  constexpr int K = 1024, N = 1024;
  __shared__ unsigned short Asm[128 * LDT];   // 18 KB
  __shared__ unsigned short Bsm[128 * LDT];   // 18 KB
  const int tid = threadIdx.x;
  const int lane = tid & 63, wid = tid >> 6;
  const int wm = wid >> 1, wn = wid & 1;
  const int l15 = lane & 15, l4 = lane >> 4;
  const int m0 = blockIdx.y * 128, n0 = blockIdx.x * 128;
  f32x4 acc[4][4] = {};

  for (int k0 = 0; k0 < K; k0 += BK) {
    __syncthreads();
#pragma unroll
    for (int i = 0; i < 4; ++i) {
      int idx = tid + 256 * i;          // 1024 chunks of 8 elems = 128x64 tile
      int row = idx >> 3, k8 = (idx & 7) * 8;
      bf16x8 va, vb;
      if constexpr (AF32) {
        va = cvt8((const float*)Av + (size_t)(m0 + row) * K + k0 + k8);
      } else if constexpr (HSPLIT) {
        const int m = m0 + row, kk = k0 + k8;
        const int bb = m >> 11, s = m & 2047;
        va = *reinterpret_cast<const bf16x8*>(
            (const unsigned short*)Av +
            (((size_t)(bb * H_ + (kk >> 6)) * S_ + s) * HD_ + (kk & 63)));
      } else {
        va = *reinterpret_cast<const bf16x8*>((const unsigned short*)Av + (size_t)(m0 + row) * K + k0 + k8);
      }
      if constexpr (BF32) {
        vb = cvt8((const float*)Bv + (size_t)(n0 + row) * K + k0 + k8);
      } else {
        vb = *reinterpret_cast<const bf16x8*>((const unsigned short*)Bv + (size_t)(n0 + row) * K + k0 + k8);
      }
      *reinterpret_cast<bf16x8*>(&Asm[row * LDT + k8]) = va;
      *reinterpret_cast<bf16x8*>(&Bsm[row * LDT + k8]) = vb;
    }
    __syncthreads();
#pragma unroll
    for (int kk = 0; kk < 2; ++kk) {
      bf16x8 af[4], bfr[4];
#pragma unroll
      for (int f = 0; f < 4; ++f) {
        af[f]  = *reinterpret_cast<const bf16x8*>(&Asm[(wm * 64 + f * 16 + l15) * LDT + kk * 32 + l4 * 8]);
        bfr[f] = *reinterpret_cast<const bf16x8*>(&Bsm[(wn * 64 + f * 16 + l15) * LDT + kk * 32 + l4 * 8]);
      }
#pragma unroll
      for (int fm = 0; fm < 4; ++fm)
#pragma unroll
        for (int fn = 0; fn < 4; ++fn)
          acc[fm][fn] = __builtin_amdgcn_mfma_f32_16x16x32_bf16(af[fm], bfr[fn], acc[fm][fn], 0, 0, 0);
    }
  }

#pragma unroll
  for (int fm = 0; fm < 4; ++fm) {
#pragma unroll
    for (int fn = 0; fn < 4; ++fn) {
      const int mg0 = m0 + wm * 64 + fm * 16 + l4 * 4;   // rows mg0..mg0+3
      const int ng  = n0 + wn * 64 + fn * 16 + l15;
      if constexpr (MODE == 0) {
        float* C = (float*)Cout;                    // FLOAT32 final output
#pragma unroll
        for (int r = 0; r < 4; ++r)
          C[(size_t)(mg0 + r) * N + ng] = acc[fm][fn][r];
      } else if constexpr (MODE == 1) {
        unsigned short* C = (unsigned short*)Cout;
        const int bidx = mg0 >> 11, s = mg0 & 2047;
        const int h = ng >> 6, d = ng & 63;
#pragma unroll
        for (int r = 0; r < 4; ++r)
          C[((size_t)((bidx * H_ + h) * S_ + s + r)) * HD_ + d] = f2bf(acc[fm][fn][r]);
      } else {
        unsigned short* C = (unsigned short*)Cout;
        const int bidx = mg0 >> 11, s = mg0 & 2047;
        const int h = ng >> 6, d = ng & 63;
        ushort4 pk;
        pk.x = f2bf(acc[fm][fn][0]); pk.y = f2bf(acc[fm][fn][1]);
        pk.z = f2bf(acc[fm][fn][2]); pk.w = f2bf(acc[fm][fn][3]);
        *reinterpret_cast<ushort4*>(&C[((size_t)((bidx * H_ + h) * HD_ + d)) * S_ + s]) = pk;
      }
    }
  }
}

// Flash-style MFMA attention with causal tile-skip (exact ref semantics).
// Future tiles (kb > q0+63) contribute exp(s+NEG-m) which underflows to
// exactly 0.0f for any row with >=1 visible unmasked key; blocks where row q0
// is degenerate (attn_mask[b,0..q0] all 0) do the full sweep instead (exact
// reference computation). Block: 4 waves, 64 q-rows. Grid: (S/64, B*H).
// ctx may alias Qh (per-wave self-overwrite of its own 16 rows).
__global__ __launch_bounds__(256) void attn_fwd(const unsigned short* Qh,
                                                const unsigned short* __restrict__ Kh,
                                                const unsigned short* __restrict__ Vt,
                                                const int* __restrict__ attn_mask,
                                                const int* __restrict__ mask_future,
                                                unsigned short* ctx) {
  constexpr int LDK = 72;  // 64+8 pad: row stride 144B -> 2-way bank alias
  __shared__ unsigned short Ksm[64 * LDK];
  __shared__ unsigned short Vsm[64 * LDK];   // d-major: Vsm[d][s_off]
  __shared__ unsigned short Psm[4][16 * LDK];
  __shared__ int msk[64];
  __shared__ int s_any;
  const int tid = threadIdx.x, lane = tid & 63, wid = tid >> 6;
  const int l15 = lane & 15, l4 = lane >> 4;
  const int bh = blockIdx.y, b = bh >> 4;
  const int q0 = blockIdx.x * 64;
  const bool causal = (mask_future[0] != 0);

  // does row q0 have any visible unmasked key? (scan attn_mask[b, 0..q0])
  if (tid == 0) s_any = 0;
  __syncthreads();
  for (int i = tid; i <= q0; i += 256)
    if (attn_mask[b * S_ + i]) s_any = 1;
  __syncthreads();
  const int kb_end = (causal && s_any) ? (q0 + 64) : S_;

  const unsigned short* Qb = Qh + (size_t)bh * S_ * HD_;
  const unsigned short* Kb = Kh + (size_t)bh * S_ * HD_;
  const unsigned short* Vb = Vt + (size_t)bh * HD_ * S_;

  const int qrow = q0 + wid * 16 + l15;
  const bf16x8 qf0 = *reinterpret_cast<const bf16x8*>(&Qb[(size_t)qrow * HD_ + l4 * 8]);
  const bf16x8 qf1 = *reinterpret_cast<const bf16x8*>(&Qb[(size_t)qrow * HD_ + 32 + l4 * 8]);

  float m_run[4], l_run[4];
  f32x4 o[4] = {};
#pragma unroll
  for (int r = 0; r < 4; ++r) { m_run[r] = -1e30f; l_run[r] = 0.f; }

  for (int kb = 0; kb < kb_end; kb += 64) {
    __syncthreads();
#pragma unroll
    for (int i = 0; i < 2; ++i) {
      int idx = tid + 256 * i;          // 512 chunks of 8 = 64x64 tile
      int row = idx >> 3, c8 = (idx & 7) * 8;
      *reinterpret_cast<bf16x8*>(&Ksm[row * LDK + c8]) =
          *reinterpret_cast<const bf16x8*>(&Kb[(size_t)(kb + row) * HD_ + c8]);
      *reinterpret_cast<bf16x8*>(&Vsm[row * LDK + c8]) =
          *reinterpret_cast<const bf16x8*>(&Vb[(size_t)row * S_ + kb + c8]);
    }
    if (tid < 64) msk[tid] = attn_mask[b * S_ + kb + tid];
    __syncthreads();

    // QK^T: D[q=(l>>4)*4+r][key=l&15] per 16-col fragment
    f32x4 sc[4];
#pragma unroll
    for (int nf = 0; nf < 4; ++nf) {
      bf16x8 kf0 = *reinterpret_cast<const bf16x8*>(&Ksm[(nf * 16 + l15) * LDK + l4 * 8]);
      bf16x8 kf1 = *reinterpret_cast<const bf16x8*>(&Ksm[(nf * 16 + l15) * LDK + 32 + l4 * 8]);
      f32x4 z = {};
      z = __builtin_amdgcn_mfma_f32_16x16x32_bf16(qf0, kf0, z, 0, 0, 0);
      z = __builtin_amdgcn_mfma_f32_16x16x32_bf16(qf1, kf1, z, 0, 0, 0);
      sc[nf] = z;
    }

    float p[4][4];
#pragma unroll
    for (int r = 0; r < 4; ++r) {
      const int rowg = q0 + wid * 16 + l4 * 4 + r;
      float mx = -1e30f;
#pragma unroll
      for (int nf = 0; nf < 4; ++nf) {
        const int colg = kb + nf * 16 + l15;
        float vv = sc[nf][r] * 0.125f;               // 1/sqrt(64)
        if (causal && colg > rowg) vv += NEGV;       // causal bias (additive)
        if (msk[nf * 16 + l15] == 0) vv = NEGV;      // pad mask (replace)
        p[nf][r] = vv;
        mx = fmaxf(mx, vv);
      }
      mx = fmaxf(mx, __shfl_xor(mx, 1));
      mx = fmaxf(mx, __shfl_xor(mx, 2));
      mx = fmaxf(mx, __shfl_xor(mx, 4));
      mx = fmaxf(mx, __shfl_xor(mx, 8));
      const float m_new = fmaxf(m_run[r], mx);
      const float scale = __expf(m_run[r] - m_new);
      float s_loc = 0.f;
#pragma unroll
      for (int nf = 0; nf < 4; ++nf) {
        float e = __expf(p[nf][r] - m_new);
        p[nf][r] = e;
        s_loc += e;
      }
      s_loc += __shfl_xor(s_loc, 1);
      s_loc += __shfl_xor(s_loc, 2);
      s_loc += __shfl_xor(s_loc, 4);
      s_loc += __shfl_xor(s_loc, 8);
      l_run[r] = l_run[r] * scale + s_loc;
      m_run[r] = m_new;
#pragma unroll
      for (int nf2 = 0; nf2 < 4; ++nf2) o[nf2][r] *= scale;
    }

    // P (C/D layout) -> LDS -> A-fragment layout
    unsigned short* Pw = &Psm[wid][0];
#pragma unroll
    for (int nf = 0; nf < 4; ++nf)
#pragma unroll
      for (int r = 0; r < 4; ++r)
        Pw[(l4 * 4 + r) * LDK + nf * 16 + l15] = f2bf(p[nf][r]);
    __syncthreads();

    const bf16x8 pf0 = *reinterpret_cast<const bf16x8*>(&Pw[l15 * LDK + l4 * 8]);
    const bf16x8 pf1 = *reinterpret_cast<const bf16x8*>(&Pw[l15 * LDK + 32 + l4 * 8]);
#pragma unroll
    for (int nf2 = 0; nf2 < 4; ++nf2) {
      bf16x8 vf0 = *reinterpret_cast<const bf16x8*>(&Vsm[(nf2 * 16 + l15) * LDK + l4 * 8]);
      bf16x8 vf1 = *reinterpret_cast<const bf16x8*>(&Vsm[(nf2 * 16 + l15) * LDK + 32 + l4 * 8]);
      o[nf2] = __builtin_amdgcn_mfma_f32_16x16x32_bf16(pf0, vf0, o[nf2], 0, 0, 0);
      o[nf2] = __builtin_amdgcn_mfma_f32_16x16x32_bf16(pf1, vf1, o[nf2], 0, 0, 0);
    }
  }

  // ctx write: head-split layout, rows q0..q0+63 of slice bh (in-place over Qh)
#pragma unroll
  for (int nf2 = 0; nf2 < 4; ++nf2)
#pragma unroll
    for (int r = 0; r < 4; ++r) {
      const int rowg = q0 + wid * 16 + l4 * 4 + r;
      float vv = o[nf2][r] / l_run[r];
      ctx[((size_t)bh * S_ + rowg) * HD_ + nf2 * 16 + l15] = f2bf(vv);
    }
}

extern "C" void kernel_launch(void* const* d_in, const int* in_sizes, int n_in,
                              void* d_out, int out_size, void* d_ws, size_t ws_size,
                              hipStream_t stream) {
  const float* q = (const float*)d_in[0];
  const float* k = (const float*)d_in[1];
  const float* v = (const float*)d_in[2];
  const int* attn_mask = (const int*)d_in[3];
  const float* Wq = (const float*)d_in[4];
  const float* Wk = (const float*)d_in[5];
  const float* Wv = (const float*)d_in[6];
  const float* Wo = (const float*)d_in[7];
  const int* mask_future = (const int*)d_in[8];

  // d_out is FLOAT32 (16.78 MB). ws usage: 16.78 MB.
  //   ws0: Qh bf16 (Q-proj) -> overwritten IN PLACE by ctx (head-split)
  //   ws1: Kh bf16 (K-proj)
  //   d_out first half: Vt bf16 (V-proj, transposed) -> dead after attn,
  //        then the O-proj GEMM overwrites ALL of d_out with f32 output.
  const size_t n16 = (size_t)M_ * D_;
  unsigned short* ws0 = (unsigned short*)d_ws;
  unsigned short* ws1 = ws0 + n16;
  unsigned short* Vt  = (unsigned short*)d_out;
  float* out = (float*)d_out;
  (void)in_sizes; (void)n_in; (void)out_size; (void)ws_size;

  dim3 gg(D_ / 128, M_ / 128);   // (8, 32)
  gemm_bt<1, true,  true,  false><<<gg, 256, 0, stream>>>(q, Wq, ws0);
  gemm_bt<1, true,  true,  false><<<gg, 256, 0, stream>>>(k, Wk, ws1);
  gemm_bt<2, true,  true,  false><<<gg, 256, 0, stream>>>(v, Wv, Vt);
  attn_fwd<<<dim3(S_ / 64, B_ * H_), 256, 0, stream>>>(ws0, ws1, Vt, attn_mask, mask_future, ws0);
  gemm_bt<0, false, true,  true ><<<gg, 256, 0, stream>>>(ws0, Wo, out);
}

// Round 9
// 256.001 us; speedup vs baseline: 1.0982x; 1.0134x over previous
//
#include <hip/hip_runtime.h>
#include <hip/hip_bf16.h>

typedef __attribute__((ext_vector_type(8))) short bf16x8;
typedef __attribute__((ext_vector_type(4))) float f32x4;

#define B_ 2
#define S_ 2048
#define D_ 1024
#define H_ 16
#define HD_ 64
#define M_ 4096
#define NEGV (-10000.0f)

static __device__ __forceinline__ unsigned short f2bf(float x) {
  __hip_bfloat16 h = __float2bfloat16(x);
  return *reinterpret_cast<unsigned short*>(&h);
}

static __device__ __forceinline__ bf16x8 cvt8(const float* p) {
  float4 a = *reinterpret_cast<const float4*>(p);
  float4 b = *reinterpret_cast<const float4*>(p + 4);
  bf16x8 r;
  r[0] = (short)f2bf(a.x); r[1] = (short)f2bf(a.y);
  r[2] = (short)f2bf(a.z); r[3] = (short)f2bf(a.w);
  r[4] = (short)f2bf(b.x); r[5] = (short)f2bf(b.y);
  r[6] = (short)f2bf(b.z); r[7] = (short)f2bf(b.w);
  return r;
}

// C = A(4096,1024) @ B(1024,1024)^T, bf16 MFMA, f32 accumulate. BK=64.
// AF32/BF32: operand is f32 (cvt on stage); else bf16.
// MODE 0: f32 row-major (final output; d_out is FLOAT32)
// MODE 1: bf16 head-split dst[((b*H+h)*S + s)*HD + d]   (Q, K)
// MODE 2: bf16 transposed  dst[((b*H+h)*HD + d)*S + s]   (V)
// HSPLIT: A is bf16 stored head-split (ctx from attention).
template<int MODE, bool AF32, bool BF32, bool HSPLIT>
__global__ __launch_bounds__(256) void gemm_bt(const void* __restrict__ Av,
                                               const void* __restrict__ Bv,
                                               void* __restrict__ Cout) {
  constexpr int BK = 64, LDT = 72;  // +8 pad: row stride 144B -> 2-way alias
  constexpr int K = 1024, N = 1024;
  __shared__ unsigned short Asm[128 * LDT];   // 18 KB
  __shared__ unsigned short Bsm[128 * LDT];   // 18 KB
  const int tid = threadIdx.x;
  const int lane = tid & 63, wid = tid >> 6;
  const int wm = wid >> 1, wn = wid & 1;
  const int l15 = lane & 15, l4 = lane >> 4;
  const int m0 = blockIdx.y * 128, n0 = blockIdx.x * 128;
  f32x4 acc[4][4] = {};

  for (int k0 = 0; k0 < K; k0 += BK) {
    __syncthreads();
#pragma unroll
    for (int i = 0; i < 4; ++i) {
      int idx = tid + 256 * i;          // 1024 chunks of 8 elems = 128x64 tile
      int row = idx >> 3, k8 = (idx & 7) * 8;
      bf16x8 va, vb;
      if constexpr (AF32) {
        va = cvt8((const float*)Av + (size_t)(m0 + row) * K + k0 + k8);
      } else if constexpr (HSPLIT) {
        const int m = m0 + row, kk = k0 + k8;
        const int bb = m >> 11, s = m & 2047;
        va = *reinterpret_cast<const bf16x8*>(
            (const unsigned short*)Av +
            (((size_t)(bb * H_ + (kk >> 6)) * S_ + s) * HD_ + (kk & 63)));
      } else {
        va = *reinterpret_cast<const bf16x8*>((const unsigned short*)Av + (size_t)(m0 + row) * K + k0 + k8);
      }
      if constexpr (BF32) {
        vb = cvt8((const float*)Bv + (size_t)(n0 + row) * K + k0 + k8);
      } else {
        vb = *reinterpret_cast<const bf16x8*>((const unsigned short*)Bv + (size_t)(n0 + row) * K + k0 + k8);
      }
      *reinterpret_cast<bf16x8*>(&Asm[row * LDT + k8]) = va;
      *reinterpret_cast<bf16x8*>(&Bsm[row * LDT + k8]) = vb;
    }
    __syncthreads();
#pragma unroll
    for (int kk = 0; kk < 2; ++kk) {
      bf16x8 af[4], bfr[4];
#pragma unroll
      for (int f = 0; f < 4; ++f) {
        af[f]  = *reinterpret_cast<const bf16x8*>(&Asm[(wm * 64 + f * 16 + l15) * LDT + kk * 32 + l4 * 8]);
        bfr[f] = *reinterpret_cast<const bf16x8*>(&Bsm[(wn * 64 + f * 16 + l15) * LDT + kk * 32 + l4 * 8]);
      }
#pragma unroll
      for (int fm = 0; fm < 4; ++fm)
#pragma unroll
        for (int fn = 0; fn < 4; ++fn)
          acc[fm][fn] = __builtin_amdgcn_mfma_f32_16x16x32_bf16(af[fm], bfr[fn], acc[fm][fn], 0, 0, 0);
    }
  }

#pragma unroll
  for (int fm = 0; fm < 4; ++fm) {
#pragma unroll
    for (int fn = 0; fn < 4; ++fn) {
      const int mg0 = m0 + wm * 64 + fm * 16 + l4 * 4;   // rows mg0..mg0+3
      const int ng  = n0 + wn * 64 + fn * 16 + l15;
      if constexpr (MODE == 0) {
        float* C = (float*)Cout;                    // FLOAT32 final output
#pragma unroll
        for (int r = 0; r < 4; ++r)
          C[(size_t)(mg0 + r) * N + ng] = acc[fm][fn][r];
      } else if constexpr (MODE == 1) {
        unsigned short* C = (unsigned short*)Cout;
        const int bidx = mg0 >> 11, s = mg0 & 2047;
        const int h = ng >> 6, d = ng & 63;
#pragma unroll
        for (int r = 0; r < 4; ++r)
          C[((size_t)((bidx * H_ + h) * S_ + s + r)) * HD_ + d] = f2bf(acc[fm][fn][r]);
      } else {
        unsigned short* C = (unsigned short*)Cout;
        const int bidx = mg0 >> 11, s = mg0 & 2047;
        const int h = ng >> 6, d = ng & 63;
        ushort4 pk;
        pk.x = f2bf(acc[fm][fn][0]); pk.y = f2bf(acc[fm][fn][1]);
        pk.z = f2bf(acc[fm][fn][2]); pk.w = f2bf(acc[fm][fn][3]);
        *reinterpret_cast<ushort4*>(&C[((size_t)((bidx * H_ + h) * HD_ + d)) * S_ + s]) = pk;
      }
    }
  }
}

// Flash-style MFMA attention, KVBLK=128, register-prefetched staging.
// Causal tile-skip is exact (see r8 comment). Block: 4 waves, 64 q-rows.
// Grid: (S/64, B*H). ctx may alias Qh (per-wave self-overwrite).
// Psm is wave-private -> no barrier between P write and P read.
__global__ __launch_bounds__(256) void attn_fwd(const unsigned short* Qh,
                                                const unsigned short* __restrict__ Kh,
                                                const unsigned short* __restrict__ Vt,
                                                const int* __restrict__ attn_mask,
                                                const int* __restrict__ mask_future,
                                                unsigned short* ctx) {
  constexpr int KVB = 128;
  constexpr int LDK = 72;    // K tile [128][64+8]
  constexpr int LDV = 136;   // V tile d-major [64][128+8]
  constexpr int LDP = 136;   // P per-wave [16][128+8]
  __shared__ unsigned short Ksm[KVB * LDK];     // 18432 B
  __shared__ unsigned short Vsm[64 * LDV];      // 17408 B
  __shared__ unsigned short Psm[4][16 * LDP];   // 17408 B
  __shared__ int msk[KVB];
  __shared__ int s_any;
  const int tid = threadIdx.x, lane = tid & 63, wid = tid >> 6;
  const int l15 = lane & 15, l4 = lane >> 4;
  const int bh = blockIdx.y, b = bh >> 4;
  const int q0 = blockIdx.x * 64;
  const bool causal = (mask_future[0] != 0);

  if (tid == 0) s_any = 0;
  __syncthreads();
  for (int i = tid; i <= q0; i += 256)
    if (attn_mask[b * S_ + i]) s_any = 1;
  __syncthreads();
  const int kb_end = (causal && s_any) ? (q0 + 64) : S_;

  const unsigned short* Qb = Qh + (size_t)bh * S_ * HD_;
  const unsigned short* Kb = Kh + (size_t)bh * S_ * HD_;
  const unsigned short* Vb = Vt + (size_t)bh * HD_ * S_;

  const int qrow = q0 + wid * 16 + l15;
  const bf16x8 qf0 = *reinterpret_cast<const bf16x8*>(&Qb[(size_t)qrow * HD_ + l4 * 8]);
  const bf16x8 qf1 = *reinterpret_cast<const bf16x8*>(&Qb[(size_t)qrow * HD_ + 32 + l4 * 8]);

  float m_run[4], l_run[4];
  f32x4 o[4] = {};
#pragma unroll
  for (int r = 0; r < 4; ++r) { m_run[r] = -1e30f; l_run[r] = 0.f; }

  // prefetch registers: K 128x64 and V 64x128 = 1024 chunks of 8 each
  bf16x8 kreg[4], vreg[4];
  int mreg = 0;
  {
    const int kb = 0;
#pragma unroll
    for (int j = 0; j < 4; ++j) {
      const int idx = tid + 256 * j;
      kreg[j] = *reinterpret_cast<const bf16x8*>(&Kb[(size_t)(kb + (idx >> 3)) * HD_ + (idx & 7) * 8]);
      vreg[j] = *reinterpret_cast<const bf16x8*>(&Vb[(size_t)(idx >> 4) * S_ + kb + (idx & 15) * 8]);
    }
    if (tid < KVB) mreg = attn_mask[b * S_ + kb + tid];
  }

  for (int kb = 0; kb < kb_end; kb += KVB) {
    __syncthreads();   // all waves done reading previous tile's LDS
#pragma unroll
    for (int j = 0; j < 4; ++j) {
      const int idx = tid + 256 * j;
      *reinterpret_cast<bf16x8*>(&Ksm[(idx >> 3) * LDK + (idx & 7) * 8]) = kreg[j];
      *reinterpret_cast<bf16x8*>(&Vsm[(idx >> 4) * LDV + (idx & 15) * 8]) = vreg[j];
    }
    if (tid < KVB) msk[tid] = mreg;
    __syncthreads();

    // issue next tile's loads now; latency hides under this tile's compute
    if (kb + KVB < kb_end) {
      const int kn = kb + KVB;
#pragma unroll
      for (int j = 0; j < 4; ++j) {
        const int idx = tid + 256 * j;
        kreg[j] = *reinterpret_cast<const bf16x8*>(&Kb[(size_t)(kn + (idx >> 3)) * HD_ + (idx & 7) * 8]);
        vreg[j] = *reinterpret_cast<const bf16x8*>(&Vb[(size_t)(idx >> 4) * S_ + kn + (idx & 15) * 8]);
      }
      if (tid < KVB) mreg = attn_mask[b * S_ + kn + tid];
    }

    // QK^T: 8 fragments of 16 keys; D[q=(l>>4)*4+r][key=l&15]
    f32x4 sc[8];
#pragma unroll
    for (int nf = 0; nf < 8; ++nf) {
      bf16x8 kf0 = *reinterpret_cast<const bf16x8*>(&Ksm[(nf * 16 + l15) * LDK + l4 * 8]);
      bf16x8 kf1 = *reinterpret_cast<const bf16x8*>(&Ksm[(nf * 16 + l15) * LDK + 32 + l4 * 8]);
      f32x4 z = {};
      z = __builtin_amdgcn_mfma_f32_16x16x32_bf16(qf0, kf0, z, 0, 0, 0);
      z = __builtin_amdgcn_mfma_f32_16x16x32_bf16(qf1, kf1, z, 0, 0, 0);
      sc[nf] = z;
    }

    unsigned short* Pw = &Psm[wid][0];
#pragma unroll
    for (int r = 0; r < 4; ++r) {
      const int rowg = q0 + wid * 16 + l4 * 4 + r;
      float mx = -1e30f;
      float pv[8];
#pragma unroll
      for (int nf = 0; nf < 8; ++nf) {
        const int colg = kb + nf * 16 + l15;
        float vv = sc[nf][r] * 0.125f;               // 1/sqrt(64)
        if (causal && colg > rowg) vv += NEGV;       // causal bias (additive)
        if (msk[nf * 16 + l15] == 0) vv = NEGV;      // pad mask (replace)
        pv[nf] = vv;
        mx = fmaxf(mx, vv);
      }
      mx = fmaxf(mx, __shfl_xor(mx, 1));
      mx = fmaxf(mx, __shfl_xor(mx, 2));
      mx = fmaxf(mx, __shfl_xor(mx, 4));
      mx = fmaxf(mx, __shfl_xor(mx, 8));
      const float m_new = fmaxf(m_run[r], mx);
      const float scale = __expf(m_run[r] - m_new);
      float s_loc = 0.f;
#pragma unroll
      for (int nf = 0; nf < 8; ++nf) {
        float e = __expf(pv[nf] - m_new);
        s_loc += e;
        Pw[(l4 * 4 + r) * LDP + nf * 16 + l15] = f2bf(e);
      }
      s_loc += __shfl_xor(s_loc, 1);
      s_loc += __shfl_xor(s_loc, 2);
      s_loc += __shfl_xor(s_loc, 4);
      s_loc += __shfl_xor(s_loc, 8);
      l_run[r] = l_run[r] * scale + s_loc;
      m_run[r] = m_new;
#pragma unroll
      for (int nf2 = 0; nf2 < 4; ++nf2) o[nf2][r] *= scale;
    }

    // PV: Psm[wid] is wave-private -> no __syncthreads needed (lgkmcnt only)
#pragma unroll
    for (int nf2 = 0; nf2 < 4; ++nf2) {
#pragma unroll
      for (int kk = 0; kk < 4; ++kk) {
        bf16x8 pf = *reinterpret_cast<const bf16x8*>(&Pw[l15 * LDP + kk * 32 + l4 * 8]);
        bf16x8 vf = *reinterpret_cast<const bf16x8*>(&Vsm[(nf2 * 16 + l15) * LDV + kk * 32 + l4 * 8]);
        o[nf2] = __builtin_amdgcn_mfma_f32_16x16x32_bf16(pf, vf, o[nf2], 0, 0, 0);
      }
    }
  }

  // ctx write: head-split layout, rows q0..q0+63 of slice bh (in-place over Qh)
#pragma unroll
  for (int nf2 = 0; nf2 < 4; ++nf2)
#pragma unroll
    for (int r = 0; r < 4; ++r) {
      const int rowg = q0 + wid * 16 + l4 * 4 + r;
      float vv = o[nf2][r] / l_run[r];
      ctx[((size_t)bh * S_ + rowg) * HD_ + nf2 * 16 + l15] = f2bf(vv);
    }
}

extern "C" void kernel_launch(void* const* d_in, const int* in_sizes, int n_in,
                              void* d_out, int out_size, void* d_ws, size_t ws_size,
                              hipStream_t stream) {
  const float* q = (const float*)d_in[0];
  const float* k = (const float*)d_in[1];
  const float* v = (const float*)d_in[2];
  const int* attn_mask = (const int*)d_in[3];
  const float* Wq = (const float*)d_in[4];
  const float* Wk = (const float*)d_in[5];
  const float* Wv = (const float*)d_in[6];
  const float* Wo = (const float*)d_in[7];
  const int* mask_future = (const int*)d_in[8];

  // d_out is FLOAT32 (16.78 MB). ws usage: 16.78 MB.
  //   ws0: Qh bf16 (Q-proj) -> overwritten IN PLACE by ctx (head-split)
  //   ws1: Kh bf16 (K-proj)
  //   d_out first half: Vt bf16 (V-proj, transposed) -> dead after attn,
  //        then the O-proj GEMM overwrites ALL of d_out with f32 output.
  const size_t n16 = (size_t)M_ * D_;
  unsigned short* ws0 = (unsigned short*)d_ws;
  unsigned short* ws1 = ws0 + n16;
  unsigned short* Vt  = (unsigned short*)d_out;
  float* out = (float*)d_out;
  (void)in_sizes; (void)n_in; (void)out_size; (void)ws_size;

  dim3 gg(D_ / 128, M_ / 128);   // (8, 32)
  gemm_bt<1, true,  true,  false><<<gg, 256, 0, stream>>>(q, Wq, ws0);
  gemm_bt<1, true,  true,  false><<<gg, 256, 0, stream>>>(k, Wk, ws1);
  gemm_bt<2, true,  true,  false><<<gg, 256, 0, stream>>>(v, Wv, Vt);
  attn_fwd<<<dim3(S_ / 64, B_ * H_), 256, 0, stream>>>(ws0, ws1, Vt, attn_mask, mask_future, ws0);
  gemm_bt<0, false, true,  true ><<<gg, 256, 0, stream>>>(ws0, Wo, out);
}